// Round 13
// baseline (314.815 us; speedup 1.0000x reference)
//
#include <hip/hip_runtime.h>
#include <math.h>

#define B_ 1024
#define N_ 64
#define F_ 512

typedef const __attribute__((address_space(1))) float* gptr_t;
typedef __attribute__((address_space(3))) float* lptr_t;
typedef _Float16 half_t;
typedef half_t half8 __attribute__((ext_vector_type(8)));
typedef half_t half4 __attribute__((ext_vector_type(4)));
typedef float f32x4 __attribute__((ext_vector_type(4)));

__device__ __forceinline__ void gload16(const float* g, float* l) {
  __builtin_amdgcn_global_load_lds((gptr_t)g, (lptr_t)l, 16, 0, 0);
}

// swizzled LDS addresses (halves): octet-XOR keeps b128 frag reads 2-way max
#define XMI(n, f) ((n) * 128 + (((((f) >> 3) ^ ((n) >> 0 & 7))) << 3) + ((f) & 7))
#define SQI(n, m) ((n) * 64 + (((((m) >> 3) ^ ((n) & 7))) << 3) + ((m) & 7))

#define MFMA3(accv, ah, al, bh, bl)                                           \
  do {                                                                        \
    accv = __builtin_amdgcn_mfma_f32_16x16x32_f16(ah, bh, accv, 0, 0, 0);     \
    accv = __builtin_amdgcn_mfma_f32_16x16x32_f16(ah, bl, accv, 0, 0, 0);     \
    accv = __builtin_amdgcn_mfma_f32_16x16x32_f16(al, bh, accv, 0, 0, 0);     \
  } while (0)

// ---------------------------------------------------------------------------
// Kernel 0: pre-split W (x512) into f16 hi/lo, transposed + swizzled.
// ---------------------------------------------------------------------------
__global__ __launch_bounds__(256) void k_split_w(const float* __restrict__ W,
                                                 half_t* __restrict__ wt_hi,
                                                 half_t* __restrict__ wt_lo) {
  int idx = blockIdx.x * 256 + threadIdx.x;  // 0..262143
  int k = idx >> 9, n = idx & 511;
  float wv = W[idx] * 512.0f;
  half_t hh = (half_t)wv;
  half_t hl = (half_t)(wv - (float)hh);
  int f = (n ^ (n >> 1)) & 3;
  int pos = ((k >> 3) & 3) ^ f;
  int addr = n * 512 + (k & ~31) + (pos << 3) + (k & 7);
  wt_hi[addr] = hh;
  wt_lo[addr] = hl;
}

// ---------------------------------------------------------------------------
// Kernel 1 v4: r12's 64x128-wave-tile kernel (correct, better LDS/MFMA
// ratio) + Kc=32 DOUBLE-BUFFERING (r11's proven skeleton) to restore the
// stage/compute overlap r12 lost. 96KB LDS, 1 block/CU, intra-block overlap.
// ---------------------------------------------------------------------------
__global__ __launch_bounds__(256, 1) void k_wh(const float* __restrict__ hA,
                                               const half_t* __restrict__ WTh,
                                               const half_t* __restrict__ WTl,
                                               float* __restrict__ Wh) {
  __shared__ float  As[2][128 * 32];   // 16KB x2 fp32
  __shared__ half_t Bh[2][256 * 32];   // 16KB x2
  __shared__ half_t Bl[2][256 * 32];   // 16KB x2  -> 96KB total

  const int bid = blockIdx.x;                    // 0..1023
  const int wg  = (bid & 7) * 128 + (bid >> 3);  // XCD-grouped (1024%8==0)
  const int mt  = wg >> 1;                       // M-tile 0..511
  const int nt  = wg & 1;                        // N-tile 0..1
  const int t = threadIdx.x;
  const int w = t >> 6, lane = t & 63;
  const int wr = w >> 1, wc = w & 1;             // wave 64x128 sub-tile
  const int lr = lane & 15, ko = lane >> 4;

  const float* Ab = hA + (size_t)mt * 128 * F_;
  const int n0 = nt * 256;

  // A staging (fp32, source-swizzled cols; proven): 4 slots/thread.
  int Asrc[4], Alds[4];
#pragma unroll
  for (int i = 0; i < 4; ++i) {
    int s = t + 256 * i;
    int row = s >> 3, j = s & 7;
    int jg = j ^ (row & 7);
    Asrc[i] = row * F_ + jg * 4;
    Alds[i] = s * 4;
  }
  // B staging from pre-split tables: 4 slots/thread per plane.
  int Bsrc[4], Blds[4];
#pragma unroll
  for (int i = 0; i < 4; ++i) {
    int s = t + 256 * i;
    int n = s >> 2, sl = s & 3;
    Bsrc[i] = (n0 + n) * 512 + sl * 8;
    Blds[i] = s * 8;
  }

  f32x4 acc[4][8];
#pragma unroll
  for (int i = 0; i < 4; ++i)
#pragma unroll
    for (int j = 0; j < 8; ++j) acc[i][j] = (f32x4){0.f, 0.f, 0.f, 0.f};

#define STAGE(buf, k0)                                                       \
  do {                                                                       \
    _Pragma("unroll") for (int i_ = 0; i_ < 4; ++i_)                         \
        gload16(Ab + (size_t)(k0) + Asrc[i_], &As[buf][Alds[i_]]);           \
    _Pragma("unroll") for (int i_ = 0; i_ < 4; ++i_)                         \
        gload16((const float*)(WTh + (size_t)(k0) + Bsrc[i_]),               \
                (float*)&Bh[buf][Blds[i_]]);                                 \
    _Pragma("unroll") for (int i_ = 0; i_ < 4; ++i_)                         \
        gload16((const float*)(WTl + (size_t)(k0) + Bsrc[i_]),               \
                (float*)&Bl[buf][Blds[i_]]);                                 \
  } while (0)

#define COMPUTE(buf)                                                         \
  do {                                                                       \
    half8 ah[4], al[4];                                                      \
    _Pragma("unroll") for (int i = 0; i < 4; ++i) {                          \
      int r = wr * 64 + i * 16 + lr;                                         \
      int p0 = (2 * ko) ^ (r & 7), p1 = (2 * ko + 1) ^ (r & 7);              \
      f32x4 x0 = *(const f32x4*)&As[buf][r * 32 + p0 * 4];                   \
      f32x4 x1 = *(const f32x4*)&As[buf][r * 32 + p1 * 4];                   \
      _Pragma("unroll") for (int q = 0; q < 4; ++q) {                        \
        float xs = x0[q] * 16.0f;                                            \
        half_t hh = (half_t)xs;                                              \
        ah[i][q] = hh;                                                       \
        al[i][q] = (half_t)(xs - (float)hh);                                 \
      }                                                                      \
      _Pragma("unroll") for (int q = 0; q < 4; ++q) {                        \
        float xs = x1[q] * 16.0f;                                            \
        half_t hh = (half_t)xs;                                              \
        ah[i][4 + q] = hh;                                                   \
        al[i][4 + q] = (half_t)(xs - (float)hh);                             \
      }                                                                      \
    }                                                                        \
    _Pragma("unroll") for (int j = 0; j < 8; ++j) {                          \
      int nb = wc * 128 + j * 16 + lr;                                       \
      int p = ko ^ ((nb ^ (nb >> 1)) & 3);                                   \
      half8 bh = *(const half8*)&Bh[buf][nb * 32 + p * 8];                   \
      half8 bl = *(const half8*)&Bl[buf][nb * 32 + p * 8];                   \
      _Pragma("unroll") for (int i = 0; i < 4; ++i)                          \
          MFMA3(acc[i][j], ah[i], al[i], bh, bl);                            \
    }                                                                        \
  } while (0)

  STAGE(0, 0);
  __syncthreads();
#pragma unroll 1
  for (int kt = 0; kt < 16; ++kt) {
    int cur = kt & 1;
    if (kt < 15) STAGE(cur ^ 1, (kt + 1) * 32);
    COMPUTE(cur);
    __syncthreads();
  }

  const float sc = 1.0f / 8192.0f;
  float* whb = Wh + ((size_t)mt * 128 + wr * 64) * F_ + n0 + wc * 128;
#pragma unroll
  for (int i = 0; i < 4; ++i) {
#pragma unroll
    for (int rr = 0; rr < 4; ++rr) {
      int row = i * 16 + ko * 4 + rr;
#pragma unroll
      for (int j = 0; j < 8; ++j)
        whb[row * F_ + j * 16 + lr] = acc[i][j][rr] * sc;
    }
  }
#undef STAGE
#undef COMPUTE
}

// ---------------------------------------------------------------------------
// Kernel 2: k_attn verbatim (passing, ~110 us).
// ---------------------------------------------------------------------------
__global__ __launch_bounds__(256) void k_attn(const float* __restrict__ Wh,
                                              const float* __restrict__ A1,
                                              const float* __restrict__ A2,
                                              const float* __restrict__ betap,
                                              float* __restrict__ out) {
  __shared__ float sm[12416];
  half_t* e_h   = (half_t*)sm;
  half_t* e_l   = e_h + 4096;
  half_t* xm_h  = (half_t*)(sm + 4096);
  half_t* xm_l  = xm_h + 8192;
  half_t* hid_h = (half_t*)(sm + 4096);
  half_t* hid_l = (half_t*)(sm + 6144);
  half_t* ab_h  = (half_t*)(sm + 8192);
  half_t* ab_l  = (half_t*)(sm + 10240);
  half_t* at_h  = (half_t*)sm;
  half_t* at_l  = at_h + 4096;
  half_t* wt_h  = (half_t*)(sm + 4096);
  half_t* wt_l  = (half_t*)(sm + 8192);
  float* mu  = sm + 12288;
  float* nrm = sm + 12352;

  const int b = blockIdx.x;
  const int t = threadIdx.x;
  const int w = t >> 6, lane = t & 63;
  const int lr = lane & 15, ko = lane >> 4;
  const float beta = betap[0];
  const float* whb = Wh + (size_t)b * N_ * F_;

  // ---- phase 1: row means ----
  {
    int n = t >> 2, q = t & 3;
    const float* row = whb + n * F_ + q * 128;
    float s = 0.f;
#pragma unroll
    for (int i = 0; i < 32; ++i) {
      float4 v = *(const float4*)(row + i * 4);
      s += v.x + v.y + v.z + v.w;
    }
    s += __shfl_xor(s, 1);
    s += __shfl_xor(s, 2);
    if (q == 0) mu[n] = s * (1.f / F_);
  }
  __syncthreads();

  // ---- phase 2: cov = Xm @ Xm^T via MFMA, 4 k-chunks of 128 ----
  f32x4 covA[4];
#pragma unroll
  for (int j = 0; j < 4; ++j) covA[j] = (f32x4){0.f, 0.f, 0.f, 0.f};

#pragma unroll 1
  for (int c = 0; c < 4; ++c) {
#pragma unroll
    for (int i = 0; i < 8; ++i) {
      int id = t + 256 * i;
      int n = id >> 5, c4 = id & 31;
      float4 v = *(const float4*)(whb + n * F_ + c * 128 + c4 * 4);
      float m_ = mu[n];
      float x0 = (v.x - m_) * 16.f, x1 = (v.y - m_) * 16.f;
      float x2 = (v.z - m_) * 16.f, x3 = (v.w - m_) * 16.f;
      half4 hh, hl;
      hh[0] = (half_t)x0; hl[0] = (half_t)(x0 - (float)hh[0]);
      hh[1] = (half_t)x1; hl[1] = (half_t)(x1 - (float)hh[1]);
      hh[2] = (half_t)x2; hl[2] = (half_t)(x2 - (float)hh[2]);
      hh[3] = (half_t)x3; hl[3] = (half_t)(x3 - (float)hh[3]);
      int ad = n * 128 + (((c4 >> 1) ^ (n & 7)) << 3) + (c4 & 1) * 4;
      *(half4*)&xm_h[ad] = hh;
      *(half4*)&xm_l[ad] = hl;
    }
    __syncthreads();
#pragma unroll
    for (int s = 0; s < 4; ++s) {
      int ra = w * 16 + lr;
      half8 ah = *(const half8*)&xm_h[XMI(ra, (s * 4 + ko) * 8)];
      half8 al = *(const half8*)&xm_l[XMI(ra, (s * 4 + ko) * 8)];
#pragma unroll
      for (int j = 0; j < 4; ++j) {
        int rb = j * 16 + lr;
        half8 bh = *(const half8*)&xm_h[XMI(rb, (s * 4 + ko) * 8)];
        half8 bl = *(const half8*)&xm_l[XMI(rb, (s * 4 + ko) * 8)];
        covA[j] = __builtin_amdgcn_mfma_f32_16x16x32_f16(ah, bh, covA[j], 0, 0, 0);
        covA[j] = __builtin_amdgcn_mfma_f32_16x16x32_f16(ah, bl, covA[j], 0, 0, 0);
        covA[j] = __builtin_amdgcn_mfma_f32_16x16x32_f16(al, bh, covA[j], 0, 0, 0);
      }
    }
    __syncthreads();
  }

  // ---- phase 3: norms from diagonal ----
#pragma unroll
  for (int r = 0; r < 4; ++r)
    if (lr == 4 * ko + r) nrm[w * 16 + lr] = sqrtf(covA[w][r]);
  __syncthreads();

  // ---- phase 4: e = beta*|corr| in regs (C-layout) + split to LDS ----
  float e32[4][4];  // [m-tile][reg]
#pragma unroll
  for (int j = 0; j < 4; ++j) {
#pragma unroll
    for (int r = 0; r < 4; ++r) {
      int n = w * 16 + 4 * ko + r;
      int m = j * 16 + lr;
      float denom = nrm[n] * nrm[m] + 2.56e-6f;  // (16nrm)(16nrm)+256*1e-8
      float e = beta * fabsf(covA[j][r] / denom);
      e32[j][r] = e;
      float es = e * 16.f;
      half_t hh = (half_t)es;
      e_h[SQI(n, m)] = hh;
      e_l[SQI(n, m)] = (half_t)(es - (float)hh);
    }
  }
  __syncthreads();

  // ---- phase 5: MLP via MFMA, K-chunked over 4 j-chunks of 64 ----
  f32x4 adj[4];
#pragma unroll
  for (int j = 0; j < 4; ++j) adj[j] = (f32x4){0.f, 0.f, 0.f, 0.f};

#pragma unroll 1
  for (int jc = 0; jc < 4; ++jc) {
    // stage A1^T chunk: ab[jl][m] = 64*A1[m][jc*64+jl]
#pragma unroll
    for (int hf = 0; hf < 2; ++hf) {
      int mo = w + 4 * hf;          // m-octet 0..7
      int jl = lane;                // 0..63
      half8 hh, hl;
#pragma unroll
      for (int q = 0; q < 8; ++q) {
        float x = A1[(size_t)(mo * 8 + q) * 256 + jc * 64 + jl] * 64.f;
        half_t h = (half_t)x;
        hh[q] = h; hl[q] = (half_t)(x - (float)h);
      }
      int ad = jl * 64 + ((mo ^ (jl & 7)) << 3);
      *(half8*)&ab_h[ad] = hh;
      *(half8*)&ab_l[ad] = hl;
    }
    __syncthreads();

    // layer1: hid = relu(e @ A1chunk)
    f32x4 h1[4];
#pragma unroll
    for (int j = 0; j < 4; ++j) h1[j] = (f32x4){0.f, 0.f, 0.f, 0.f};
#pragma unroll
    for (int s = 0; s < 2; ++s) {
      int ra = w * 16 + lr;
      half8 ah = *(const half8*)&e_h[SQI(ra, (s * 4 + ko) * 8)];
      half8 al = *(const half8*)&e_l[SQI(ra, (s * 4 + ko) * 8)];
#pragma unroll
      for (int jt = 0; jt < 4; ++jt) {
        int jl = jt * 16 + lr;
        half8 bh = *(const half8*)&ab_h[SQI(jl, (s * 4 + ko) * 8)];
        half8 bl = *(const half8*)&ab_l[SQI(jl, (s * 4 + ko) * 8)];
        h1[jt] = __builtin_amdgcn_mfma_f32_16x16x32_f16(ah, bh, h1[jt], 0, 0, 0);
        h1[jt] = __builtin_amdgcn_mfma_f32_16x16x32_f16(ah, bl, h1[jt], 0, 0, 0);
        h1[jt] = __builtin_amdgcn_mfma_f32_16x16x32_f16(al, bh, h1[jt], 0, 0, 0);
      }
    }
    // relu + split -> hid
#pragma unroll
    for (int jt = 0; jt < 4; ++jt) {
#pragma unroll
      for (int r = 0; r < 4; ++r) {
        float x = fmaxf(h1[jt][r], 0.f);
        int n = w * 16 + 4 * ko + r;
        int jl = jt * 16 + lr;
        half_t hh = (half_t)x;
        hid_h[SQI(n, jl)] = hh;
        hid_l[SQI(n, jl)] = (half_t)(x - (float)hh);
      }
    }
    __syncthreads();

    // stage A2 chunk: ab[m][kl] = 64*A2[jc*64+kl][m]
#pragma unroll
    for (int hf = 0; hf < 2; ++hf) {
      int ko2 = w + 4 * hf;         // kl-octet 0..7
      int m = lane;                 // 0..63
      half8 hh, hl;
#pragma unroll
      for (int q = 0; q < 8; ++q) {
        float x = A2[(size_t)(jc * 64 + ko2 * 8 + q) * 64 + m] * 64.f;
        half_t h = (half_t)x;
        hh[q] = h; hl[q] = (half_t)(x - (float)h);
      }
      int ad = m * 64 + ((ko2 ^ (m & 7)) << 3);
      *(half8*)&ab_h[ad] = hh;
      *(half8*)&ab_l[ad] = hl;
    }
    __syncthreads();

    // layer2: adj += hid @ A2chunk
#pragma unroll
    for (int s = 0; s < 2; ++s) {
      int ra = w * 16 + lr;
      half8 ah = *(const half8*)&hid_h[SQI(ra, (s * 4 + ko) * 8)];
      half8 al = *(const half8*)&hid_l[SQI(ra, (s * 4 + ko) * 8)];
#pragma unroll
      for (int mt = 0; mt < 4; ++mt) {
        int m = mt * 16 + lr;
        half8 bh = *(const half8*)&ab_h[SQI(m, (s * 4 + ko) * 8)];
        half8 bl = *(const half8*)&ab_l[SQI(m, (s * 4 + ko) * 8)];
        adj[mt] = __builtin_amdgcn_mfma_f32_16x16x32_f16(ah, bh, adj[mt], 0, 0, 0);
        adj[mt] = __builtin_amdgcn_mfma_f32_16x16x32_f16(ah, bl, adj[mt], 0, 0, 0);
        adj[mt] = __builtin_amdgcn_mfma_f32_16x16x32_f16(al, bh, adj[mt], 0, 0, 0);
      }
    }
    __syncthreads();
  }

  // ---- phase 6: mask + row-softmax in regs, split probs -> at_hl ----
  {
    float p[4][4];
#pragma unroll
    for (int r = 0; r < 4; ++r) {
      float mx = -3.0e38f;
#pragma unroll
      for (int mt = 0; mt < 4; ++mt) {
        float pre = e32[mt][r] + adj[mt][r] * (1.f / 65536.f);
        p[mt][r] = (pre > 0.f) ? e32[mt][r] : -1e12f;
        mx = fmaxf(mx, p[mt][r]);
      }
      mx = fmaxf(mx, __shfl_xor(mx, 1));
      mx = fmaxf(mx, __shfl_xor(mx, 2));
      mx = fmaxf(mx, __shfl_xor(mx, 4));
      mx = fmaxf(mx, __shfl_xor(mx, 8));
      float ssum = 0.f;
#pragma unroll
      for (int mt = 0; mt < 4; ++mt) {
        p[mt][r] = expf(p[mt][r] - mx);
        ssum += p[mt][r];
      }
      ssum += __shfl_xor(ssum, 1);
      ssum += __shfl_xor(ssum, 2);
      ssum += __shfl_xor(ssum, 4);
      ssum += __shfl_xor(ssum, 8);
      float inv = 1.f / ssum;
      int n = w * 16 + 4 * ko + r;
#pragma unroll
      for (int mt = 0; mt < 4; ++mt) {
        float pv = p[mt][r] * inv;
        int m = mt * 16 + lr;
        half_t hh = (half_t)pv;
        at_h[SQI(n, m)] = hh;
        at_l[SQI(n, m)] = (half_t)(pv - (float)hh);
      }
    }
  }

  // ---- phase 7: out = attn @ Wh via MFMA, 4 f-chunks of 128 ----
  const int fl0 = t & 127;   // f-local row 0..127
  const int moB = t >> 7;    // m-octet base 0..1
#pragma unroll 1
  for (int fc = 0; fc < 4; ++fc) {
    __syncthreads();
#pragma unroll
    for (int i = 0; i < 4; ++i) {
      int mo = moB + 2 * i;  // m-octet 0..7
      half8 hh, hl;
#pragma unroll
      for (int q = 0; q < 8; ++q) {
        float x = whb[(size_t)(mo * 8 + q) * F_ + fc * 128 + fl0];
        half_t h = (half_t)x;
        hh[q] = h; hl[q] = (half_t)(x - (float)h);
      }
      int ad = fl0 * 64 + ((mo ^ (fl0 & 7)) << 3);
      *(half8*)&wt_h[ad] = hh;
      *(half8*)&wt_l[ad] = hl;
    }
    __syncthreads();

    half8 aah[2], aal[2];
#pragma unroll
    for (int s = 0; s < 2; ++s) {
      int n = w * 16 + lr;
      aah[s] = *(const half8*)&at_h[SQI(n, (s * 4 + ko) * 8)];
      aal[s] = *(const half8*)&at_l[SQI(n, (s * 4 + ko) * 8)];
    }
#pragma unroll
    for (int ft = 0; ft < 8; ++ft) {
      f32x4 po = (f32x4){0.f, 0.f, 0.f, 0.f};
#pragma unroll
      for (int s = 0; s < 2; ++s) {
        int fl = ft * 16 + lr;
        int ad = fl * 64 + (((((s * 4 + ko)) ^ (fl & 7))) << 3);
        half8 bh = *(const half8*)&wt_h[ad];
        half8 bl = *(const half8*)&wt_l[ad];
        po = __builtin_amdgcn_mfma_f32_16x16x32_f16(aah[s], bh, po, 0, 0, 0);
        po = __builtin_amdgcn_mfma_f32_16x16x32_f16(aah[s], bl, po, 0, 0, 0);
        po = __builtin_amdgcn_mfma_f32_16x16x32_f16(aal[s], bh, po, 0, 0, 0);
      }
      int fg = fc * 128 + ft * 16 + lr;
#pragma unroll
      for (int r = 0; r < 4; ++r) {
        int n = w * 16 + 4 * ko + r;
        out[(size_t)b * N_ * F_ + n * F_ + fg] = po[r];
      }
    }
  }
}

extern "C" void kernel_launch(void* const* d_in, const int* in_sizes, int n_in,
                              void* d_out, int out_size, void* d_ws, size_t ws_size,
                              hipStream_t stream) {
  const float* h    = (const float*)d_in[0];
  const float* W    = (const float*)d_in[1];
  const float* beta = (const float*)d_in[2];
  const float* A1   = (const float*)d_in[3];
  const float* A2   = (const float*)d_in[4];
  float* out = (float*)d_out;
  float* Wh  = (float*)d_ws;  // 128 MiB workspace

  half_t* wt_hi = (half_t*)d_out;
  half_t* wt_lo = wt_hi + 512 * 512;

  k_split_w<<<1024, 256, 0, stream>>>(W, wt_hi, wt_lo);
  k_wh<<<1024, 256, 0, stream>>>(h, wt_hi, wt_lo, Wh);
  k_attn<<<B_, 256, 0, stream>>>(Wh, A1, A2, beta, out);
}

// Round 14
// 261.282 us; speedup vs baseline: 1.2049x; 1.2049x over previous
//
#include <hip/hip_runtime.h>
#include <math.h>

#define B_ 1024
#define N_ 64
#define F_ 512

typedef const __attribute__((address_space(1))) float* gptr_t;
typedef __attribute__((address_space(3))) float* lptr_t;
typedef _Float16 half_t;
typedef half_t half8 __attribute__((ext_vector_type(8)));
typedef half_t half4 __attribute__((ext_vector_type(4)));
typedef float f32x4 __attribute__((ext_vector_type(4)));

__device__ __forceinline__ void gload16(const float* g, float* l) {
  __builtin_amdgcn_global_load_lds((gptr_t)g, (lptr_t)l, 16, 0, 0);
}

// swizzled LDS addresses (halves): octet-XOR keeps b128 frag reads 2-way max
#define XMI(n, f) ((n) * 128 + (((((f) >> 3) ^ ((n) >> 0 & 7))) << 3) + ((f) & 7))
#define SQI(n, m) ((n) * 64 + (((((m) >> 3) ^ ((n) & 7))) << 3) + ((m) & 7))

#define MFMA3(accv, ah, al, bh, bl)                                           \
  do {                                                                        \
    accv = __builtin_amdgcn_mfma_f32_16x16x32_f16(ah, bh, accv, 0, 0, 0);     \
    accv = __builtin_amdgcn_mfma_f32_16x16x32_f16(ah, bl, accv, 0, 0, 0);     \
    accv = __builtin_amdgcn_mfma_f32_16x16x32_f16(al, bh, accv, 0, 0, 0);     \
  } while (0)

// ---------------------------------------------------------------------------
// Kernel 0: pre-split W (x512) into f16 hi/lo, transposed + swizzled.
// ---------------------------------------------------------------------------
__global__ __launch_bounds__(256) void k_split_w(const float* __restrict__ W,
                                                 half_t* __restrict__ wt_hi,
                                                 half_t* __restrict__ wt_lo) {
  int idx = blockIdx.x * 256 + threadIdx.x;  // 0..262143
  int k = idx >> 9, n = idx & 511;
  float wv = W[idx] * 512.0f;
  half_t hh = (half_t)wv;
  half_t hl = (half_t)(wv - (float)hh);
  int f = (n ^ (n >> 1)) & 3;
  int pos = ((k >> 3) & 3) ^ f;
  int addr = n * 512 + (k & ~31) + (pos << 3) + (k & 7);
  wt_hi[addr] = hh;
  wt_lo[addr] = hl;
}

// ---------------------------------------------------------------------------
// Kernel 1 v5: r11's 128x128 tile (best measured) with 48KB LDS ->
// 3 blocks/CU. A fp32 SINGLE-buffered (split on read, r12/r13-proven);
// B hi/lo double-buffered (r11-proven). Extra raw s_barrier mid-step
// protects the single A buffer. Math bit-identical to r11.
// ---------------------------------------------------------------------------
__global__ __launch_bounds__(256, 3) void k_wh(const float* __restrict__ hA,
                                               const half_t* __restrict__ WTh,
                                               const half_t* __restrict__ WTl,
                                               float* __restrict__ Wh) {
  __shared__ float  As[128 * 32];      // 16KB fp32, single buffer
  __shared__ half_t Bh[2][128 * 32];   // 8KB x2
  __shared__ half_t Bl[2][128 * 32];   // 8KB x2   -> 48KB total

  const int bid = blockIdx.x;                    // 0..2047
  const int wg  = (bid & 7) * 256 + (bid >> 3);  // XCD-grouped (2048%8==0)
  const int mt  = wg >> 2;                       // M-tile 0..511
  const int nt  = wg & 3;                        // N-tile 0..3
  const int t = threadIdx.x;
  const int w = t >> 6, lane = t & 63;
  const int wr = w >> 1, wc = w & 1;             // wave 64x64 sub-tile
  const int lr = lane & 15, ko = lane >> 4;

  const float* Ab = hA + (size_t)mt * 128 * F_;
  const int n0 = nt * 128;

  // A staging (fp32, source-swizzled cols; proven r9): 4 slots/thread.
  int Asrc[4], Alds[4];
#pragma unroll
  for (int i = 0; i < 4; ++i) {
    int s = t + 256 * i;
    int row = s >> 3, j = s & 7;
    int jg = j ^ (row & 7);
    Asrc[i] = row * F_ + jg * 4;
    Alds[i] = s * 4;
  }
  // B staging from pre-split tables (proven r11): 2 slots/thread/plane.
  int Bsrc[2], Blds[2];
#pragma unroll
  for (int i = 0; i < 2; ++i) {
    int s = t + 256 * i;
    int n = s >> 2, sl = s & 3;
    Bsrc[i] = (n0 + n) * 512 + sl * 8;
    Blds[i] = s * 8;
  }

  f32x4 acc[4][4];
#pragma unroll
  for (int i = 0; i < 4; ++i)
#pragma unroll
    for (int j = 0; j < 4; ++j) acc[i][j] = (f32x4){0.f, 0.f, 0.f, 0.f};

#define STAGE_A(k0)                                                          \
  do {                                                                       \
    _Pragma("unroll") for (int i_ = 0; i_ < 4; ++i_)                         \
        gload16(Ab + (size_t)(k0) + Asrc[i_], &As[Alds[i_]]);                \
  } while (0)

#define STAGE_B(buf, k0)                                                     \
  do {                                                                       \
    _Pragma("unroll") for (int i_ = 0; i_ < 2; ++i_)                         \
        gload16((const float*)(WTh + (size_t)(k0) + Bsrc[i_]),               \
                (float*)&Bh[buf][Blds[i_]]);                                 \
    _Pragma("unroll") for (int i_ = 0; i_ < 2; ++i_)                         \
        gload16((const float*)(WTl + (size_t)(k0) + Bsrc[i_]),               \
                (float*)&Bl[buf][Blds[i_]]);                                 \
  } while (0)

  STAGE_B(0, 0);
  STAGE_A(0);
  __syncthreads();

#pragma unroll 1
  for (int kt = 0; kt < 16; ++kt) {
    const int cur = kt & 1;
    // (1) issue next B prefetch into the idle B buffer (read-safe: all
    //     waves passed last step's __syncthreads after consuming it).
    if (kt < 15) STAGE_B(cur ^ 1, (kt + 1) * 32);

    // (2) read + split A fragments from the single A buffer. The split
    //     VALU consumes the ds_reads, so they are retired before (3).
    half8 ah[4], al[4];
#pragma unroll
    for (int i = 0; i < 4; ++i) {
      int r = wr * 64 + i * 16 + lr;
      int p0 = (2 * ko) ^ (r & 7), p1 = (2 * ko + 1) ^ (r & 7);
      f32x4 x0 = *(const f32x4*)&As[r * 32 + p0 * 4];
      f32x4 x1 = *(const f32x4*)&As[r * 32 + p1 * 4];
#pragma unroll
      for (int q = 0; q < 4; ++q) {
        float xs = x0[q] * 16.0f;
        half_t hh = (half_t)xs;
        ah[i][q] = hh;
        al[i][q] = (half_t)(xs - (float)hh);
      }
#pragma unroll
      for (int q = 0; q < 4; ++q) {
        float xs = x1[q] * 16.0f;
        half_t hh = (half_t)xs;
        ah[i][4 + q] = hh;
        al[i][4 + q] = (half_t)(xs - (float)hh);
      }
    }

    // (3) all waves finished reading A -> safe to overwrite it.
    __builtin_amdgcn_sched_barrier(0);
    __builtin_amdgcn_s_barrier();
    __builtin_amdgcn_sched_barrier(0);

    // (4) issue next A prefetch into the (now idle) A buffer.
    if (kt < 15) STAGE_A((kt + 1) * 32);

    // (5) MFMA with B[cur] fragments (B reads don't touch A region).
#pragma unroll
    for (int j = 0; j < 4; ++j) {
      int nb = wc * 64 + j * 16 + lr;
      int p = ko ^ ((nb ^ (nb >> 1)) & 3);
      half8 bh = *(const half8*)&Bh[cur][nb * 32 + p * 8];
      half8 bl = *(const half8*)&Bl[cur][nb * 32 + p * 8];
#pragma unroll
      for (int i = 0; i < 4; ++i) MFMA3(acc[i][j], ah[i], al[i], bh, bl);
    }

    // (6) full drain: next-step A and B data landed; everyone synced.
    __syncthreads();
  }

  const float sc = 1.0f / 8192.0f;
  float* whb = Wh + ((size_t)mt * 128 + wr * 64) * F_ + n0 + wc * 64;
#pragma unroll
  for (int i = 0; i < 4; ++i) {
#pragma unroll
    for (int rr = 0; rr < 4; ++rr) {
      int row = i * 16 + ko * 4 + rr;
#pragma unroll
      for (int j = 0; j < 4; ++j)
        whb[row * F_ + j * 16 + lr] = acc[i][j][rr] * sc;
    }
  }
#undef STAGE_A
#undef STAGE_B
}

// ---------------------------------------------------------------------------
// Kernel 2: k_attn verbatim (passing, ~110 us).
// ---------------------------------------------------------------------------
__global__ __launch_bounds__(256) void k_attn(const float* __restrict__ Wh,
                                              const float* __restrict__ A1,
                                              const float* __restrict__ A2,
                                              const float* __restrict__ betap,
                                              float* __restrict__ out) {
  __shared__ float sm[12416];
  half_t* e_h   = (half_t*)sm;
  half_t* e_l   = e_h + 4096;
  half_t* xm_h  = (half_t*)(sm + 4096);
  half_t* xm_l  = xm_h + 8192;
  half_t* hid_h = (half_t*)(sm + 4096);
  half_t* hid_l = (half_t*)(sm + 6144);
  half_t* ab_h  = (half_t*)(sm + 8192);
  half_t* ab_l  = (half_t*)(sm + 10240);
  half_t* at_h  = (half_t*)sm;
  half_t* at_l  = at_h + 4096;
  half_t* wt_h  = (half_t*)(sm + 4096);
  half_t* wt_l  = (half_t*)(sm + 8192);
  float* mu  = sm + 12288;
  float* nrm = sm + 12352;

  const int b = blockIdx.x;
  const int t = threadIdx.x;
  const int w = t >> 6, lane = t & 63;
  const int lr = lane & 15, ko = lane >> 4;
  const float beta = betap[0];
  const float* whb = Wh + (size_t)b * N_ * F_;

  // ---- phase 1: row means ----
  {
    int n = t >> 2, q = t & 3;
    const float* row = whb + n * F_ + q * 128;
    float s = 0.f;
#pragma unroll
    for (int i = 0; i < 32; ++i) {
      float4 v = *(const float4*)(row + i * 4);
      s += v.x + v.y + v.z + v.w;
    }
    s += __shfl_xor(s, 1);
    s += __shfl_xor(s, 2);
    if (q == 0) mu[n] = s * (1.f / F_);
  }
  __syncthreads();

  // ---- phase 2: cov = Xm @ Xm^T via MFMA, 4 k-chunks of 128 ----
  f32x4 covA[4];
#pragma unroll
  for (int j = 0; j < 4; ++j) covA[j] = (f32x4){0.f, 0.f, 0.f, 0.f};

#pragma unroll 1
  for (int c = 0; c < 4; ++c) {
#pragma unroll
    for (int i = 0; i < 8; ++i) {
      int id = t + 256 * i;
      int n = id >> 5, c4 = id & 31;
      float4 v = *(const float4*)(whb + n * F_ + c * 128 + c4 * 4);
      float m_ = mu[n];
      float x0 = (v.x - m_) * 16.f, x1 = (v.y - m_) * 16.f;
      float x2 = (v.z - m_) * 16.f, x3 = (v.w - m_) * 16.f;
      half4 hh, hl;
      hh[0] = (half_t)x0; hl[0] = (half_t)(x0 - (float)hh[0]);
      hh[1] = (half_t)x1; hl[1] = (half_t)(x1 - (float)hh[1]);
      hh[2] = (half_t)x2; hl[2] = (half_t)(x2 - (float)hh[2]);
      hh[3] = (half_t)x3; hl[3] = (half_t)(x3 - (float)hh[3]);
      int ad = n * 128 + (((c4 >> 1) ^ (n & 7)) << 3) + (c4 & 1) * 4;
      *(half4*)&xm_h[ad] = hh;
      *(half4*)&xm_l[ad] = hl;
    }
    __syncthreads();
#pragma unroll
    for (int s = 0; s < 4; ++s) {
      int ra = w * 16 + lr;
      half8 ah = *(const half8*)&xm_h[XMI(ra, (s * 4 + ko) * 8)];
      half8 al = *(const half8*)&xm_l[XMI(ra, (s * 4 + ko) * 8)];
#pragma unroll
      for (int j = 0; j < 4; ++j) {
        int rb = j * 16 + lr;
        half8 bh = *(const half8*)&xm_h[XMI(rb, (s * 4 + ko) * 8)];
        half8 bl = *(const half8*)&xm_l[XMI(rb, (s * 4 + ko) * 8)];
        covA[j] = __builtin_amdgcn_mfma_f32_16x16x32_f16(ah, bh, covA[j], 0, 0, 0);
        covA[j] = __builtin_amdgcn_mfma_f32_16x16x32_f16(ah, bl, covA[j], 0, 0, 0);
        covA[j] = __builtin_amdgcn_mfma_f32_16x16x32_f16(al, bh, covA[j], 0, 0, 0);
      }
    }
    __syncthreads();
  }

  // ---- phase 3: norms from diagonal ----
#pragma unroll
  for (int r = 0; r < 4; ++r)
    if (lr == 4 * ko + r) nrm[w * 16 + lr] = sqrtf(covA[w][r]);
  __syncthreads();

  // ---- phase 4: e = beta*|corr| in regs (C-layout) + split to LDS ----
  float e32[4][4];  // [m-tile][reg]
#pragma unroll
  for (int j = 0; j < 4; ++j) {
#pragma unroll
    for (int r = 0; r < 4; ++r) {
      int n = w * 16 + 4 * ko + r;
      int m = j * 16 + lr;
      float denom = nrm[n] * nrm[m] + 2.56e-6f;  // (16nrm)(16nrm)+256*1e-8
      float e = beta * fabsf(covA[j][r] / denom);
      e32[j][r] = e;
      float es = e * 16.f;
      half_t hh = (half_t)es;
      e_h[SQI(n, m)] = hh;
      e_l[SQI(n, m)] = (half_t)(es - (float)hh);
    }
  }
  __syncthreads();

  // ---- phase 5: MLP via MFMA, K-chunked over 4 j-chunks of 64 ----
  f32x4 adj[4];
#pragma unroll
  for (int j = 0; j < 4; ++j) adj[j] = (f32x4){0.f, 0.f, 0.f, 0.f};

#pragma unroll 1
  for (int jc = 0; jc < 4; ++jc) {
    // stage A1^T chunk: ab[jl][m] = 64*A1[m][jc*64+jl]
#pragma unroll
    for (int hf = 0; hf < 2; ++hf) {
      int mo = w + 4 * hf;          // m-octet 0..7
      int jl = lane;                // 0..63
      half8 hh, hl;
#pragma unroll
      for (int q = 0; q < 8; ++q) {
        float x = A1[(size_t)(mo * 8 + q) * 256 + jc * 64 + jl] * 64.f;
        half_t h = (half_t)x;
        hh[q] = h; hl[q] = (half_t)(x - (float)h);
      }
      int ad = jl * 64 + ((mo ^ (jl & 7)) << 3);
      *(half8*)&ab_h[ad] = hh;
      *(half8*)&ab_l[ad] = hl;
    }
    __syncthreads();

    // layer1: hid = relu(e @ A1chunk)
    f32x4 h1[4];
#pragma unroll
    for (int j = 0; j < 4; ++j) h1[j] = (f32x4){0.f, 0.f, 0.f, 0.f};
#pragma unroll
    for (int s = 0; s < 2; ++s) {
      int ra = w * 16 + lr;
      half8 ah = *(const half8*)&e_h[SQI(ra, (s * 4 + ko) * 8)];
      half8 al = *(const half8*)&e_l[SQI(ra, (s * 4 + ko) * 8)];
#pragma unroll
      for (int jt = 0; jt < 4; ++jt) {
        int jl = jt * 16 + lr;
        half8 bh = *(const half8*)&ab_h[SQI(jl, (s * 4 + ko) * 8)];
        half8 bl = *(const half8*)&ab_l[SQI(jl, (s * 4 + ko) * 8)];
        h1[jt] = __builtin_amdgcn_mfma_f32_16x16x32_f16(ah, bh, h1[jt], 0, 0, 0);
        h1[jt] = __builtin_amdgcn_mfma_f32_16x16x32_f16(ah, bl, h1[jt], 0, 0, 0);
        h1[jt] = __builtin_amdgcn_mfma_f32_16x16x32_f16(al, bh, h1[jt], 0, 0, 0);
      }
    }
    // relu + split -> hid
#pragma unroll
    for (int jt = 0; jt < 4; ++jt) {
#pragma unroll
      for (int r = 0; r < 4; ++r) {
        float x = fmaxf(h1[jt][r], 0.f);
        int n = w * 16 + 4 * ko + r;
        int jl = jt * 16 + lr;
        half_t hh = (half_t)x;
        hid_h[SQI(n, jl)] = hh;
        hid_l[SQI(n, jl)] = (half_t)(x - (float)hh);
      }
    }
    __syncthreads();

    // stage A2 chunk: ab[m][kl] = 64*A2[jc*64+kl][m]
#pragma unroll
    for (int hf = 0; hf < 2; ++hf) {
      int ko2 = w + 4 * hf;         // kl-octet 0..7
      int m = lane;                 // 0..63
      half8 hh, hl;
#pragma unroll
      for (int q = 0; q < 8; ++q) {
        float x = A2[(size_t)(jc * 64 + ko2 * 8 + q) * 64 + m] * 64.f;
        half_t h = (half_t)x;
        hh[q] = h; hl[q] = (half_t)(x - (float)h);
      }
      int ad = m * 64 + ((ko2 ^ (m & 7)) << 3);
      *(half8*)&ab_h[ad] = hh;
      *(half8*)&ab_l[ad] = hl;
    }
    __syncthreads();

    // layer2: adj += hid @ A2chunk
#pragma unroll
    for (int s = 0; s < 2; ++s) {
      int ra = w * 16 + lr;
      half8 ah = *(const half8*)&hid_h[SQI(ra, (s * 4 + ko) * 8)];
      half8 al = *(const half8*)&hid_l[SQI(ra, (s * 4 + ko) * 8)];
#pragma unroll
      for (int mt = 0; mt < 4; ++mt) {
        int m = mt * 16 + lr;
        half8 bh = *(const half8*)&ab_h[SQI(m, (s * 4 + ko) * 8)];
        half8 bl = *(const half8*)&ab_l[SQI(m, (s * 4 + ko) * 8)];
        adj[mt] = __builtin_amdgcn_mfma_f32_16x16x32_f16(ah, bh, adj[mt], 0, 0, 0);
        adj[mt] = __builtin_amdgcn_mfma_f32_16x16x32_f16(ah, bl, adj[mt], 0, 0, 0);
        adj[mt] = __builtin_amdgcn_mfma_f32_16x16x32_f16(al, bh, adj[mt], 0, 0, 0);
      }
    }
    __syncthreads();
  }

  // ---- phase 6: mask + row-softmax in regs, split probs -> at_hl ----
  {
    float p[4][4];
#pragma unroll
    for (int r = 0; r < 4; ++r) {
      float mx = -3.0e38f;
#pragma unroll
      for (int mt = 0; mt < 4; ++mt) {
        float pre = e32[mt][r] + adj[mt][r] * (1.f / 65536.f);
        p[mt][r] = (pre > 0.f) ? e32[mt][r] : -1e12f;
        mx = fmaxf(mx, p[mt][r]);
      }
      mx = fmaxf(mx, __shfl_xor(mx, 1));
      mx = fmaxf(mx, __shfl_xor(mx, 2));
      mx = fmaxf(mx, __shfl_xor(mx, 4));
      mx = fmaxf(mx, __shfl_xor(mx, 8));
      float ssum = 0.f;
#pragma unroll
      for (int mt = 0; mt < 4; ++mt) {
        p[mt][r] = expf(p[mt][r] - mx);
        ssum += p[mt][r];
      }
      ssum += __shfl_xor(ssum, 1);
      ssum += __shfl_xor(ssum, 2);
      ssum += __shfl_xor(ssum, 4);
      ssum += __shfl_xor(ssum, 8);
      float inv = 1.f / ssum;
      int n = w * 16 + 4 * ko + r;
#pragma unroll
      for (int mt = 0; mt < 4; ++mt) {
        float pv = p[mt][r] * inv;
        int m = mt * 16 + lr;
        half_t hh = (half_t)pv;
        at_h[SQI(n, m)] = hh;
        at_l[SQI(n, m)] = (half_t)(pv - (float)hh);
      }
    }
  }

  // ---- phase 7: out = attn @ Wh via MFMA, 4 f-chunks of 128 ----
  const int fl0 = t & 127;   // f-local row 0..127
  const int moB = t >> 7;    // m-octet base 0..1
#pragma unroll 1
  for (int fc = 0; fc < 4; ++fc) {
    __syncthreads();
#pragma unroll
    for (int i = 0; i < 4; ++i) {
      int mo = moB + 2 * i;  // m-octet 0..7
      half8 hh, hl;
#pragma unroll
      for (int q = 0; q < 8; ++q) {
        float x = whb[(size_t)(mo * 8 + q) * F_ + fc * 128 + fl0];
        half_t h = (half_t)x;
        hh[q] = h; hl[q] = (half_t)(x - (float)h);
      }
      int ad = fl0 * 64 + ((mo ^ (fl0 & 7)) << 3);
      *(half8*)&wt_h[ad] = hh;
      *(half8*)&wt_l[ad] = hl;
    }
    __syncthreads();

    half8 aah[2], aal[2];
#pragma unroll
    for (int s = 0; s < 2; ++s) {
      int n = w * 16 + lr;
      aah[s] = *(const half8*)&at_h[SQI(n, (s * 4 + ko) * 8)];
      aal[s] = *(const half8*)&at_l[SQI(n, (s * 4 + ko) * 8)];
    }
#pragma unroll
    for (int ft = 0; ft < 8; ++ft) {
      f32x4 po = (f32x4){0.f, 0.f, 0.f, 0.f};
#pragma unroll
      for (int s = 0; s < 2; ++s) {
        int fl = ft * 16 + lr;
        int ad = fl * 64 + (((((s * 4 + ko)) ^ (fl & 7))) << 3);
        half8 bh = *(const half8*)&wt_h[ad];
        half8 bl = *(const half8*)&wt_l[ad];
        po = __builtin_amdgcn_mfma_f32_16x16x32_f16(aah[s], bh, po, 0, 0, 0);
        po = __builtin_amdgcn_mfma_f32_16x16x32_f16(aah[s], bl, po, 0, 0, 0);
        po = __builtin_amdgcn_mfma_f32_16x16x32_f16(aal[s], bh, po, 0, 0, 0);
      }
      int fg = fc * 128 + ft * 16 + lr;
#pragma unroll
      for (int r = 0; r < 4; ++r) {
        int n = w * 16 + 4 * ko + r;
        out[(size_t)b * N_ * F_ + n * F_ + fg] = po[r];
      }
    }
  }
}

extern "C" void kernel_launch(void* const* d_in, const int* in_sizes, int n_in,
                              void* d_out, int out_size, void* d_ws, size_t ws_size,
                              hipStream_t stream) {
  const float* h    = (const float*)d_in[0];
  const float* W    = (const float*)d_in[1];
  const float* beta = (const float*)d_in[2];
  const float* A1   = (const float*)d_in[3];
  const float* A2   = (const float*)d_in[4];
  float* out = (float*)d_out;
  float* Wh  = (float*)d_ws;  // 128 MiB workspace

  half_t* wt_hi = (half_t*)d_out;
  half_t* wt_lo = wt_hi + 512 * 512;

  k_split_w<<<1024, 256, 0, stream>>>(W, wt_hi, wt_lo);
  k_wh<<<2048, 256, 0, stream>>>(h, wt_hi, wt_lo, Wh);
  k_attn<<<B_, 256, 0, stream>>>(Wh, A1, A2, beta, out);
}

// Round 15
// 222.402 us; speedup vs baseline: 1.4155x; 1.1748x over previous
//
#include <hip/hip_runtime.h>
#include <math.h>

#define B_ 1024
#define N_ 64
#define F_ 512

typedef const __attribute__((address_space(1))) float* gptr_t;
typedef __attribute__((address_space(3))) float* lptr_t;
typedef _Float16 half_t;
typedef half_t half8 __attribute__((ext_vector_type(8)));
typedef half_t half4 __attribute__((ext_vector_type(4)));
typedef float f32x4 __attribute__((ext_vector_type(4)));

__device__ __forceinline__ void gload16(const float* g, float* l) {
  __builtin_amdgcn_global_load_lds((gptr_t)g, (lptr_t)l, 16, 0, 0);
}

// swizzled LDS addresses (halves): octet-XOR keeps b128 frag reads 2-way max
#define XMI(n, f) ((n) * 128 + (((((f) >> 3) ^ ((n) >> 0 & 7))) << 3) + ((f) & 7))
#define SQI(n, m) ((n) * 64 + (((((m) >> 3) ^ ((n) & 7))) << 3) + ((m) & 7))

#define MFMA3(accv, ah, al, bh, bl)                                           \
  do {                                                                        \
    accv = __builtin_amdgcn_mfma_f32_16x16x32_f16(ah, bh, accv, 0, 0, 0);     \
    accv = __builtin_amdgcn_mfma_f32_16x16x32_f16(ah, bl, accv, 0, 0, 0);     \
    accv = __builtin_amdgcn_mfma_f32_16x16x32_f16(al, bh, accv, 0, 0, 0);     \
  } while (0)

// ---------------------------------------------------------------------------
// Kernel 0: pre-split W (x512) into f16 hi/lo, transposed + swizzled.
// ---------------------------------------------------------------------------
__global__ __launch_bounds__(256) void k_split_w(const float* __restrict__ W,
                                                 half_t* __restrict__ wt_hi,
                                                 half_t* __restrict__ wt_lo) {
  int idx = blockIdx.x * 256 + threadIdx.x;  // 0..262143
  int k = idx >> 9, n = idx & 511;
  float wv = W[idx] * 512.0f;
  half_t hh = (half_t)wv;
  half_t hl = (half_t)(wv - (float)hh);
  int f = (n ^ (n >> 1)) & 3;
  int pos = ((k >> 3) & 3) ^ f;
  int addr = n * 512 + (k & ~31) + (pos << 3) + (k & 7);
  wt_hi[addr] = hh;
  wt_lo[addr] = hl;
}

// ---------------------------------------------------------------------------
// Kernel 1 v5 (r14, proven): 128x128 tile, 48KB LDS -> 3 blocks/CU.
// A fp32 single-buffered (split on read); B hi/lo double-buffered.
// ---------------------------------------------------------------------------
__global__ __launch_bounds__(256, 3) void k_wh(const float* __restrict__ hA,
                                               const half_t* __restrict__ WTh,
                                               const half_t* __restrict__ WTl,
                                               float* __restrict__ Wh) {
  __shared__ float  As[128 * 32];      // 16KB fp32, single buffer
  __shared__ half_t Bh[2][128 * 32];   // 8KB x2
  __shared__ half_t Bl[2][128 * 32];   // 8KB x2   -> 48KB total

  const int bid = blockIdx.x;                    // 0..2047
  const int wg  = (bid & 7) * 256 + (bid >> 3);  // XCD-grouped (2048%8==0)
  const int mt  = wg >> 2;                       // M-tile 0..511
  const int nt  = wg & 3;                        // N-tile 0..3
  const int t = threadIdx.x;
  const int w = t >> 6, lane = t & 63;
  const int wr = w >> 1, wc = w & 1;             // wave 64x64 sub-tile
  const int lr = lane & 15, ko = lane >> 4;

  const float* Ab = hA + (size_t)mt * 128 * F_;
  const int n0 = nt * 128;

  int Asrc[4], Alds[4];
#pragma unroll
  for (int i = 0; i < 4; ++i) {
    int s = t + 256 * i;
    int row = s >> 3, j = s & 7;
    int jg = j ^ (row & 7);
    Asrc[i] = row * F_ + jg * 4;
    Alds[i] = s * 4;
  }
  int Bsrc[2], Blds[2];
#pragma unroll
  for (int i = 0; i < 2; ++i) {
    int s = t + 256 * i;
    int n = s >> 2, sl = s & 3;
    Bsrc[i] = (n0 + n) * 512 + sl * 8;
    Blds[i] = s * 8;
  }

  f32x4 acc[4][4];
#pragma unroll
  for (int i = 0; i < 4; ++i)
#pragma unroll
    for (int j = 0; j < 4; ++j) acc[i][j] = (f32x4){0.f, 0.f, 0.f, 0.f};

#define STAGE_A(k0)                                                          \
  do {                                                                       \
    _Pragma("unroll") for (int i_ = 0; i_ < 4; ++i_)                         \
        gload16(Ab + (size_t)(k0) + Asrc[i_], &As[Alds[i_]]);                \
  } while (0)

#define STAGE_B(buf, k0)                                                     \
  do {                                                                       \
    _Pragma("unroll") for (int i_ = 0; i_ < 2; ++i_)                         \
        gload16((const float*)(WTh + (size_t)(k0) + Bsrc[i_]),               \
                (float*)&Bh[buf][Blds[i_]]);                                 \
    _Pragma("unroll") for (int i_ = 0; i_ < 2; ++i_)                         \
        gload16((const float*)(WTl + (size_t)(k0) + Bsrc[i_]),               \
                (float*)&Bl[buf][Blds[i_]]);                                 \
  } while (0)

  STAGE_B(0, 0);
  STAGE_A(0);
  __syncthreads();

#pragma unroll 1
  for (int kt = 0; kt < 16; ++kt) {
    const int cur = kt & 1;
    if (kt < 15) STAGE_B(cur ^ 1, (kt + 1) * 32);

    half8 ah[4], al[4];
#pragma unroll
    for (int i = 0; i < 4; ++i) {
      int r = wr * 64 + i * 16 + lr;
      int p0 = (2 * ko) ^ (r & 7), p1 = (2 * ko + 1) ^ (r & 7);
      f32x4 x0 = *(const f32x4*)&As[r * 32 + p0 * 4];
      f32x4 x1 = *(const f32x4*)&As[r * 32 + p1 * 4];
#pragma unroll
      for (int q = 0; q < 4; ++q) {
        float xs = x0[q] * 16.0f;
        half_t hh = (half_t)xs;
        ah[i][q] = hh;
        al[i][q] = (half_t)(xs - (float)hh);
      }
#pragma unroll
      for (int q = 0; q < 4; ++q) {
        float xs = x1[q] * 16.0f;
        half_t hh = (half_t)xs;
        ah[i][4 + q] = hh;
        al[i][4 + q] = (half_t)(xs - (float)hh);
      }
    }

    __builtin_amdgcn_sched_barrier(0);
    __builtin_amdgcn_s_barrier();
    __builtin_amdgcn_sched_barrier(0);

    if (kt < 15) STAGE_A((kt + 1) * 32);

#pragma unroll
    for (int j = 0; j < 4; ++j) {
      int nb = wc * 64 + j * 16 + lr;
      int p = ko ^ ((nb ^ (nb >> 1)) & 3);
      half8 bh = *(const half8*)&Bh[cur][nb * 32 + p * 8];
      half8 bl = *(const half8*)&Bl[cur][nb * 32 + p * 8];
#pragma unroll
      for (int i = 0; i < 4; ++i) MFMA3(acc[i][j], ah[i], al[i], bh, bl);
    }

    __syncthreads();
  }

  const float sc = 1.0f / 8192.0f;
  float* whb = Wh + ((size_t)mt * 128 + wr * 64) * F_ + n0 + wc * 64;
#pragma unroll
  for (int i = 0; i < 4; ++i) {
#pragma unroll
    for (int rr = 0; rr < 4; ++rr) {
      int row = i * 16 + ko * 4 + rr;
#pragma unroll
      for (int j = 0; j < 4; ++j)
        whb[row * F_ + j * 16 + lr] = acc[i][j][rr] * sc;
    }
  }
#undef STAGE_A
#undef STAGE_B
}

// ---------------------------------------------------------------------------
// Kernel 2: r14 k_attn + T14 async-STAGE split on phases 2/5/7: global loads
// issued into registers during the previous chunk's compute; the split+LDS
// write stays at the original staging point. Barriers and LDS addresses
// unchanged; arithmetic bit-identical.
// ---------------------------------------------------------------------------
__global__ __launch_bounds__(256) void k_attn(const float* __restrict__ Wh,
                                              const float* __restrict__ A1,
                                              const float* __restrict__ A2,
                                              const float* __restrict__ betap,
                                              float* __restrict__ out) {
  __shared__ float sm[12416];
  half_t* e_h   = (half_t*)sm;
  half_t* e_l   = e_h + 4096;
  half_t* xm_h  = (half_t*)(sm + 4096);
  half_t* xm_l  = xm_h + 8192;
  half_t* hid_h = (half_t*)(sm + 4096);
  half_t* hid_l = (half_t*)(sm + 6144);
  half_t* ab_h  = (half_t*)(sm + 8192);
  half_t* ab_l  = (half_t*)(sm + 10240);
  half_t* at_h  = (half_t*)sm;
  half_t* at_l  = at_h + 4096;
  half_t* wt_h  = (half_t*)(sm + 4096);
  half_t* wt_l  = (half_t*)(sm + 8192);
  float* mu  = sm + 12288;
  float* nrm = sm + 12352;

  const int b = blockIdx.x;
  const int t = threadIdx.x;
  const int w = t >> 6, lane = t & 63;
  const int lr = lane & 15, ko = lane >> 4;
  const float beta = betap[0];
  const float* whb = Wh + (size_t)b * N_ * F_;

  // ---- phase 1: row means (+ prefetch cov chunk 0 under the barrier) ----
  float4 vbuf[8];
#define LOAD_XM(c_)                                                           \
  do {                                                                        \
    _Pragma("unroll") for (int i_ = 0; i_ < 8; ++i_) {                        \
      int id_ = t + 256 * i_;                                                 \
      int n_ = id_ >> 5, c4_ = id_ & 31;                                      \
      vbuf[i_] = *(const float4*)(whb + n_ * F_ + (c_) * 128 + c4_ * 4);      \
    }                                                                         \
  } while (0)

  {
    int n = t >> 2, q = t & 3;
    const float* row = whb + n * F_ + q * 128;
    float s = 0.f;
#pragma unroll
    for (int i = 0; i < 32; ++i) {
      float4 v = *(const float4*)(row + i * 4);
      s += v.x + v.y + v.z + v.w;
    }
    s += __shfl_xor(s, 1);
    s += __shfl_xor(s, 2);
    if (q == 0) mu[n] = s * (1.f / F_);
  }
  LOAD_XM(0);
  __syncthreads();

  // ---- phase 2: cov = Xm @ Xm^T via MFMA, 4 k-chunks of 128 ----
  f32x4 covA[4];
#pragma unroll
  for (int j = 0; j < 4; ++j) covA[j] = (f32x4){0.f, 0.f, 0.f, 0.f};

#pragma unroll 1
  for (int c = 0; c < 4; ++c) {
    // WRITE: split vbuf (centered, x16) into xm
#pragma unroll
    for (int i = 0; i < 8; ++i) {
      int id = t + 256 * i;
      int n = id >> 5, c4 = id & 31;
      float4 v = vbuf[i];
      float m_ = mu[n];
      float x0 = (v.x - m_) * 16.f, x1 = (v.y - m_) * 16.f;
      float x2 = (v.z - m_) * 16.f, x3 = (v.w - m_) * 16.f;
      half4 hh, hl;
      hh[0] = (half_t)x0; hl[0] = (half_t)(x0 - (float)hh[0]);
      hh[1] = (half_t)x1; hl[1] = (half_t)(x1 - (float)hh[1]);
      hh[2] = (half_t)x2; hl[2] = (half_t)(x2 - (float)hh[2]);
      hh[3] = (half_t)x3; hl[3] = (half_t)(x3 - (float)hh[3]);
      int ad = n * 128 + (((c4 >> 1) ^ (n & 7)) << 3) + (c4 & 1) * 4;
      *(half4*)&xm_h[ad] = hh;
      *(half4*)&xm_l[ad] = hl;
    }
    __syncthreads();
    if (c < 3) LOAD_XM(c + 1);  // prefetch next chunk under the MFMAs
#pragma unroll
    for (int s = 0; s < 4; ++s) {
      int ra = w * 16 + lr;
      half8 ah = *(const half8*)&xm_h[XMI(ra, (s * 4 + ko) * 8)];
      half8 al = *(const half8*)&xm_l[XMI(ra, (s * 4 + ko) * 8)];
#pragma unroll
      for (int j = 0; j < 4; ++j) {
        int rb = j * 16 + lr;
        half8 bh = *(const half8*)&xm_h[XMI(rb, (s * 4 + ko) * 8)];
        half8 bl = *(const half8*)&xm_l[XMI(rb, (s * 4 + ko) * 8)];
        covA[j] = __builtin_amdgcn_mfma_f32_16x16x32_f16(ah, bh, covA[j], 0, 0, 0);
        covA[j] = __builtin_amdgcn_mfma_f32_16x16x32_f16(ah, bl, covA[j], 0, 0, 0);
        covA[j] = __builtin_amdgcn_mfma_f32_16x16x32_f16(al, bh, covA[j], 0, 0, 0);
      }
    }
    __syncthreads();
  }
#undef LOAD_XM

  // ---- phase 3: norms from diagonal ----
#pragma unroll
  for (int r = 0; r < 4; ++r)
    if (lr == 4 * ko + r) nrm[w * 16 + lr] = sqrtf(covA[w][r]);
  __syncthreads();

  // ---- phase 4: e = beta*|corr| in regs (C-layout) + split to LDS ----
  float e32[4][4];  // [m-tile][reg]
#pragma unroll
  for (int j = 0; j < 4; ++j) {
#pragma unroll
    for (int r = 0; r < 4; ++r) {
      int n = w * 16 + 4 * ko + r;
      int m = j * 16 + lr;
      float denom = nrm[n] * nrm[m] + 2.56e-6f;  // (16nrm)(16nrm)+256*1e-8
      float e = beta * fabsf(covA[j][r] / denom);
      e32[j][r] = e;
      float es = e * 16.f;
      half_t hh = (half_t)es;
      e_h[SQI(n, m)] = hh;
      e_l[SQI(n, m)] = (half_t)(es - (float)hh);
    }
  }

  // ---- phase 5: MLP via MFMA, K-chunked, T14-prefetched ----
  float a1buf[16], a2buf[16];
#define LOAD_A1(jc_)                                                          \
  do {                                                                        \
    _Pragma("unroll") for (int hf_ = 0; hf_ < 2; ++hf_)                       \
      _Pragma("unroll") for (int q_ = 0; q_ < 8; ++q_)                        \
        a1buf[hf_ * 8 + q_] =                                                 \
            A1[(size_t)((w + 4 * hf_) * 8 + q_) * 256 + (jc_) * 64 + lane];   \
  } while (0)
#define LOAD_A2(jc_)                                                          \
  do {                                                                        \
    _Pragma("unroll") for (int hf_ = 0; hf_ < 2; ++hf_)                       \
      _Pragma("unroll") for (int q_ = 0; q_ < 8; ++q_)                        \
        a2buf[hf_ * 8 + q_] =                                                 \
            A2[(size_t)((jc_) * 64 + (w + 4 * hf_) * 8 + q_) * 64 + lane];    \
  } while (0)

  LOAD_A1(0);
  __syncthreads();  // phase-4 e writes complete

  f32x4 adj[4];
#pragma unroll
  for (int j = 0; j < 4; ++j) adj[j] = (f32x4){0.f, 0.f, 0.f, 0.f};

#pragma unroll 1
  for (int jc = 0; jc < 4; ++jc) {
    // WRITE A1 chunk: ab[jl][m] = 64*A1[m][jc*64+jl]
#pragma unroll
    for (int hf = 0; hf < 2; ++hf) {
      int mo = w + 4 * hf;
      int jl = lane;
      half8 hh, hl;
#pragma unroll
      for (int q = 0; q < 8; ++q) {
        float x = a1buf[hf * 8 + q] * 64.f;
        half_t h = (half_t)x;
        hh[q] = h; hl[q] = (half_t)(x - (float)h);
      }
      int ad = jl * 64 + ((mo ^ (jl & 7)) << 3);
      *(half8*)&ab_h[ad] = hh;
      *(half8*)&ab_l[ad] = hl;
    }
    __syncthreads();
    LOAD_A2(jc);  // prefetch under layer1

    // layer1: hid = relu(e @ A1chunk)
    f32x4 h1[4];
#pragma unroll
    for (int j = 0; j < 4; ++j) h1[j] = (f32x4){0.f, 0.f, 0.f, 0.f};
#pragma unroll
    for (int s = 0; s < 2; ++s) {
      int ra = w * 16 + lr;
      half8 ah = *(const half8*)&e_h[SQI(ra, (s * 4 + ko) * 8)];
      half8 al = *(const half8*)&e_l[SQI(ra, (s * 4 + ko) * 8)];
#pragma unroll
      for (int jt = 0; jt < 4; ++jt) {
        int jl = jt * 16 + lr;
        half8 bh = *(const half8*)&ab_h[SQI(jl, (s * 4 + ko) * 8)];
        half8 bl = *(const half8*)&ab_l[SQI(jl, (s * 4 + ko) * 8)];
        h1[jt] = __builtin_amdgcn_mfma_f32_16x16x32_f16(ah, bh, h1[jt], 0, 0, 0);
        h1[jt] = __builtin_amdgcn_mfma_f32_16x16x32_f16(ah, bl, h1[jt], 0, 0, 0);
        h1[jt] = __builtin_amdgcn_mfma_f32_16x16x32_f16(al, bh, h1[jt], 0, 0, 0);
      }
    }
#pragma unroll
    for (int jt = 0; jt < 4; ++jt) {
#pragma unroll
      for (int r = 0; r < 4; ++r) {
        float x = fmaxf(h1[jt][r], 0.f);
        int n = w * 16 + 4 * ko + r;
        int jl = jt * 16 + lr;
        half_t hh = (half_t)x;
        hid_h[SQI(n, jl)] = hh;
        hid_l[SQI(n, jl)] = (half_t)(x - (float)hh);
      }
    }
    __syncthreads();

    // WRITE A2 chunk: ab[m][kl] = 64*A2[jc*64+kl][m]
#pragma unroll
    for (int hf = 0; hf < 2; ++hf) {
      int ko2 = w + 4 * hf;
      int m = lane;
      half8 hh, hl;
#pragma unroll
      for (int q = 0; q < 8; ++q) {
        float x = a2buf[hf * 8 + q] * 64.f;
        half_t h = (half_t)x;
        hh[q] = h; hl[q] = (half_t)(x - (float)h);
      }
      int ad = m * 64 + ((ko2 ^ (m & 7)) << 3);
      *(half8*)&ab_h[ad] = hh;
      *(half8*)&ab_l[ad] = hl;
    }
    __syncthreads();
    if (jc < 3) LOAD_A1(jc + 1);  // prefetch under layer2

    // layer2: adj += hid @ A2chunk
#pragma unroll
    for (int s = 0; s < 2; ++s) {
      int ra = w * 16 + lr;
      half8 ah = *(const half8*)&hid_h[SQI(ra, (s * 4 + ko) * 8)];
      half8 al = *(const half8*)&hid_l[SQI(ra, (s * 4 + ko) * 8)];
#pragma unroll
      for (int mt = 0; mt < 4; ++mt) {
        int m = mt * 16 + lr;
        half8 bh = *(const half8*)&ab_h[SQI(m, (s * 4 + ko) * 8)];
        half8 bl = *(const half8*)&ab_l[SQI(m, (s * 4 + ko) * 8)];
        adj[mt] = __builtin_amdgcn_mfma_f32_16x16x32_f16(ah, bh, adj[mt], 0, 0, 0);
        adj[mt] = __builtin_amdgcn_mfma_f32_16x16x32_f16(ah, bl, adj[mt], 0, 0, 0);
        adj[mt] = __builtin_amdgcn_mfma_f32_16x16x32_f16(al, bh, adj[mt], 0, 0, 0);
      }
    }
    __syncthreads();
  }
#undef LOAD_A1
#undef LOAD_A2

  // ---- phase 6: mask + row-softmax in regs, split probs -> at_hl ----
  {
    float p[4][4];
#pragma unroll
    for (int r = 0; r < 4; ++r) {
      float mx = -3.0e38f;
#pragma unroll
      for (int mt = 0; mt < 4; ++mt) {
        float pre = e32[mt][r] + adj[mt][r] * (1.f / 65536.f);
        p[mt][r] = (pre > 0.f) ? e32[mt][r] : -1e12f;
        mx = fmaxf(mx, p[mt][r]);
      }
      mx = fmaxf(mx, __shfl_xor(mx, 1));
      mx = fmaxf(mx, __shfl_xor(mx, 2));
      mx = fmaxf(mx, __shfl_xor(mx, 4));
      mx = fmaxf(mx, __shfl_xor(mx, 8));
      float ssum = 0.f;
#pragma unroll
      for (int mt = 0; mt < 4; ++mt) {
        p[mt][r] = expf(p[mt][r] - mx);
        ssum += p[mt][r];
      }
      ssum += __shfl_xor(ssum, 1);
      ssum += __shfl_xor(ssum, 2);
      ssum += __shfl_xor(ssum, 4);
      ssum += __shfl_xor(ssum, 8);
      float inv = 1.f / ssum;
      int n = w * 16 + 4 * ko + r;
#pragma unroll
      for (int mt = 0; mt < 4; ++mt) {
        float pv = p[mt][r] * inv;
        int m = mt * 16 + lr;
        half_t hh = (half_t)pv;
        at_h[SQI(n, m)] = hh;
        at_l[SQI(n, m)] = (half_t)(pv - (float)hh);
      }
    }
  }

  // ---- phase 7: out = attn @ Wh via MFMA, T14-prefetched chunks ----
  const int fl0 = t & 127;   // f-local row 0..127
  const int moB = t >> 7;    // m-octet base 0..1
  float wbuf[32];
#define LOAD_WT(fc_)                                                          \
  do {                                                                        \
    _Pragma("unroll") for (int i_ = 0; i_ < 4; ++i_) {                        \
      int mo_ = moB + 2 * i_;                                                 \
      _Pragma("unroll") for (int q_ = 0; q_ < 8; ++q_)                        \
        wbuf[i_ * 8 + q_] =                                                   \
            whb[(size_t)(mo_ * 8 + q_) * F_ + (fc_) * 128 + fl0];             \
    }                                                                         \
  } while (0)

  LOAD_WT(0);
#pragma unroll 1
  for (int fc = 0; fc < 4; ++fc) {
    __syncthreads();  // at writes done / previous chunk's wt reads done
    // WRITE: split wbuf into wt[fl][m]
#pragma unroll
    for (int i = 0; i < 4; ++i) {
      int mo = moB + 2 * i;
      half8 hh, hl;
#pragma unroll
      for (int q = 0; q < 8; ++q) {
        float x = wbuf[i * 8 + q];
        half_t h = (half_t)x;
        hh[q] = h; hl[q] = (half_t)(x - (float)h);
      }
      int ad = fl0 * 64 + ((mo ^ (fl0 & 7)) << 3);
      *(half8*)&wt_h[ad] = hh;
      *(half8*)&wt_l[ad] = hl;
    }
    __syncthreads();
    if (fc < 3) LOAD_WT(fc + 1);  // prefetch under the MFMAs

    half8 aah[2], aal[2];
#pragma unroll
    for (int s = 0; s < 2; ++s) {
      int n = w * 16 + lr;
      aah[s] = *(const half8*)&at_h[SQI(n, (s * 4 + ko) * 8)];
      aal[s] = *(const half8*)&at_l[SQI(n, (s * 4 + ko) * 8)];
    }
#pragma unroll
    for (int ft = 0; ft < 8; ++ft) {
      f32x4 po = (f32x4){0.f, 0.f, 0.f, 0.f};
#pragma unroll
      for (int s = 0; s < 2; ++s) {
        int fl = ft * 16 + lr;
        int ad = fl * 64 + (((((s * 4 + ko)) ^ (fl & 7))) << 3);
        half8 bh = *(const half8*)&wt_h[ad];
        half8 bl = *(const half8*)&wt_l[ad];
        po = __builtin_amdgcn_mfma_f32_16x16x32_f16(aah[s], bh, po, 0, 0, 0);
        po = __builtin_amdgcn_mfma_f32_16x16x32_f16(aah[s], bl, po, 0, 0, 0);
        po = __builtin_amdgcn_mfma_f32_16x16x32_f16(aal[s], bh, po, 0, 0, 0);
      }
      int fg = fc * 128 + ft * 16 + lr;
#pragma unroll
      for (int r = 0; r < 4; ++r) {
        int n = w * 16 + 4 * ko + r;
        out[(size_t)b * N_ * F_ + n * F_ + fg] = po[r];
      }
    }
  }
#undef LOAD_WT
}

extern "C" void kernel_launch(void* const* d_in, const int* in_sizes, int n_in,
                              void* d_out, int out_size, void* d_ws, size_t ws_size,
                              hipStream_t stream) {
  const float* h    = (const float*)d_in[0];
  const float* W    = (const float*)d_in[1];
  const float* beta = (const float*)d_in[2];
  const float* A1   = (const float*)d_in[3];
  const float* A2   = (const float*)d_in[4];
  float* out = (float*)d_out;
  float* Wh  = (float*)d_ws;  // 128 MiB workspace

  half_t* wt_hi = (half_t*)d_out;
  half_t* wt_lo = wt_hi + 512 * 512;

  k_split_w<<<1024, 256, 0, stream>>>(W, wt_hi, wt_lo);
  k_wh<<<2048, 256, 0, stream>>>(h, wt_hi, wt_lo, Wh);
  k_attn<<<B_, 256, 0, stream>>>(Wh, A1, A2, beta, out);
}